// Round 1
// baseline (347.880 us; speedup 1.0000x reference)
//
#include <hip/hip_runtime.h>

// out[b,o,l] = sum_i x[b,i,k'(l)] * P[i,o,f'(l)],  k'=idx[l]&4095, f'=idx[l]>>12
// Phase 1: xT[b,k,i] = bf16(x[b,i,k])  (coalesced transpose+cast into d_ws)
// Phase 2: expanded-K (256) bf16 MFMA GEMM, M=o(64), N=l(64-tile), gathered B.

typedef __attribute__((ext_vector_type(8))) short short8;
typedef __attribute__((ext_vector_type(4))) float floatx4;

#define NB    64
#define CIN   64
#define COUT  64
#define KDIM  4096
#define LDIM  16384
#define BXS   264   // padded LDS row stride (bf16 elems); 528B = 33*16B, bank-uniform
#define ITERS 8     // l-tiles (of 64) per block

__device__ __forceinline__ unsigned short f2bf(float f) {
  union { float f; unsigned u; } v; v.f = f;
  unsigned r = v.u + 0x7FFFu + ((v.u >> 16) & 1u);  // RNE
  return (unsigned short)(r >> 16);
}

__global__ __launch_bounds__(256) void transpose_bf16(const float* __restrict__ x,
                                                      unsigned short* __restrict__ xt) {
  __shared__ float tile[64 * 65];  // [i][k], +1 pad
  const int t = threadIdx.x;
  const int b = blockIdx.y;
  const int k0 = blockIdx.x * 64;
  const float4* x4 = (const float4*)x;
#pragma unroll
  for (int p = 0; p < 4; ++p) {
    int i  = p * 16 + (t >> 4);
    int kq = t & 15;
    float4 v = x4[(size_t)(b * CIN + i) * (KDIM / 4) + (k0 >> 2) + kq];
    tile[i * 65 + kq * 4 + 0] = v.x;
    tile[i * 65 + kq * 4 + 1] = v.y;
    tile[i * 65 + kq * 4 + 2] = v.z;
    tile[i * 65 + kq * 4 + 3] = v.w;
  }
  __syncthreads();
  unsigned int* xt32 = (unsigned int*)xt;
  const int ip = (t & 31) * 2;  // pair of i's packed into one u32 store
#pragma unroll
  for (int p = 0; p < 8; ++p) {
    int k = p * 8 + (t >> 5);
    unsigned lo = f2bf(tile[ip * 65 + k]);
    unsigned hi = f2bf(tile[(ip + 1) * 65 + k]);
    xt32[((size_t)b * KDIM + k0 + k) * (CIN / 2) + (ip >> 1)] = lo | (hi << 16);
  }
}

__global__ __launch_bounds__(256) void gemm_gather(const unsigned short* __restrict__ xt,
                                                   const float* __restrict__ params,
                                                   const int* __restrict__ idx,
                                                   float* __restrict__ out) {
  __shared__ __align__(16) unsigned short Bx[64 * BXS];  // B'[l_loc][s], s in [0,256)
  const int t = threadIdx.x;
  const int b = blockIdx.y;
  const int w = t >> 6;          // wave id = m-tile (o-tile)
  const int lane = t & 63;
  const int quad = lane >> 4;
  const int lane15 = lane & 15;

  // A' fragments in registers: A'[o][s] = P[s&63][o][s>>6], o = w*16 + lane15.
  // mfma A layout: m = lane&15, k = quad*8 + j.
  short8 afrag[8];
  {
    const int o = w * 16 + lane15;
#pragma unroll
    for (int kt = 0; kt < 8; ++kt) {
      short8 a;
#pragma unroll
      for (int j = 0; j < 8; ++j) {
        int s = kt * 32 + quad * 8 + j;
        int i = s & 63, g = s >> 6;
        a[j] = (short)f2bf(params[(i * COUT + o) * 4 + g]);
      }
      afrag[kt] = a;
    }
  }

  // fill mapping: 4 threads per l-row; thread owns 16B-chunks {2u,2u+1} of each slot
  const int u = t & 3;
  const int lrow = t >> 2;
  const uint4 zero4 = make_uint4(0u, 0u, 0u, 0u);

  for (int it = 0; it < ITERS; ++it) {
    const int l_base = (blockIdx.x * ITERS + it) * 64;

    // ---- build B' tile ----
    const int iv = idx[l_base + lrow];
    const int kp = iv & (KDIM - 1);
    const int fp = iv >> 12;
    const uint4* xrow = (const uint4*)(xt + ((size_t)b * KDIM + kp) * CIN);
    uint4 d0 = xrow[2 * u];
    uint4 d1 = xrow[2 * u + 1];
#pragma unroll
    for (int g = 0; g < 4; ++g) {
      uint4 w0 = (g == fp) ? d0 : zero4;
      uint4 w1 = (g == fp) ? d1 : zero4;
      *(uint4*)&Bx[lrow * BXS + g * 64 + (2 * u) * 8]     = w0;
      *(uint4*)&Bx[lrow * BXS + g * 64 + (2 * u + 1) * 8] = w1;
    }
    __syncthreads();

    // ---- MFMA: D[o][l] += A'[o][s] * B'[s][l] ----
    floatx4 acc[4] = {floatx4{0.f,0.f,0.f,0.f}, floatx4{0.f,0.f,0.f,0.f},
                      floatx4{0.f,0.f,0.f,0.f}, floatx4{0.f,0.f,0.f,0.f}};
#pragma unroll
    for (int kt = 0; kt < 8; ++kt) {
#pragma unroll
      for (int nt = 0; nt < 4; ++nt) {
        short8 bf = *(const short8*)&Bx[(nt * 16 + lane15) * BXS + kt * 32 + quad * 8];
        acc[nt] = __builtin_amdgcn_mfma_f32_16x16x32_bf16(afrag[kt], bf, acc[nt], 0, 0, 0);
      }
    }

    // C layout: col(n=l) = lane&15, row(m=o) = quad*4 + r
#pragma unroll
    for (int nt = 0; nt < 4; ++nt) {
      const int l = l_base + nt * 16 + lane15;
#pragma unroll
      for (int r = 0; r < 4; ++r) {
        const int o = w * 16 + quad * 4 + r;
        out[((size_t)(b * COUT + o)) * LDIM + l] = acc[nt][r];
      }
    }
    __syncthreads();  // protect Bx before next fill
  }
}

extern "C" void kernel_launch(void* const* d_in, const int* in_sizes, int n_in,
                              void* d_out, int out_size, void* d_ws, size_t ws_size,
                              hipStream_t stream) {
  const float* x      = (const float*)d_in[0];   // [64,64,1,4096] fp32
  const float* params = (const float*)d_in[1];   // [64,64,4] fp32
  const int*   idx    = (const int*)d_in[2];     // [16384] int32
  float* out = (float*)d_out;                    // [64,64,1,16384] fp32
  unsigned short* xt = (unsigned short*)d_ws;    // bf16 xT[b][k][i], 33.5 MB

  transpose_bf16<<<dim3(KDIM / 64, NB), 256, 0, stream>>>(x, xt);
  gemm_gather<<<dim3(LDIM / 64 / ITERS, NB), 256, 0, stream>>>(xt, params, idx, out);
}